// Round 1
// baseline (837.663 us; speedup 1.0000x reference)
//
#include <hip/hip_runtime.h>
#include <math.h>

#define B_  16
#define T_  4096
#define C_  64
#define K_  1024
#define KE_ 1023
#define BT_ (B_ * T_)

#define NBLK_ASSIGN 1024            // 64 queries per block
#define NBLK_SMOOTH 16380           // B*(T-1)*C / 256

// ---------------- ws layout (bytes) ----------------
// [64,    4160)   float ee[1024]        (|e_k|^2, ee[1023] = +inf pad)
// [4160,  266304) int   idxv[BT]
// [266304,528448) int   selpos[BT]
// [528448,528512) int   nst[B]
// [528512,532608) float commit_part[1024]
// [532608,536704) float valid_part[1024]
// [536704,602240) float smooth_part[16384]

// ---- |e_k|^2 precompute (k indexes e = codebook[1:], 1023 rows) ----
__global__ __launch_bounds__(256) void k_ee(const float* __restrict__ cb,
                                            float* __restrict__ ee) {
    int k = blockIdx.x * 256 + threadIdx.x;
    if (k < KE_) {
        const float* r = cb + (size_t)(k + 1) * C_;
        float s = 0.f;
        #pragma unroll
        for (int c = 0; c < C_; ++c) s = fmaf(r[c], r[c], s);
        ee[k] = s;
    } else if (k == KE_) {
        ee[k] = INFINITY;           // pad so k=1023 never wins
    }
}

// ---- hot kernel: normalize + argmin + z_q writeback + commit/valid partials
// Block = 256 threads = 4 waves. All 4 waves hold the SAME 64 queries
// (q = blockIdx*64 + lane); wave w scans code partition [w*256, w*256+256).
// Codebook addresses are wave-uniform -> s_load (SMEM pipe), VALU stays on fmac.
__global__ __launch_bounds__(256) void k_assign(
    const float* __restrict__ z, const float* __restrict__ cb,
    const float* __restrict__ mask, const float* __restrict__ ee,
    float* __restrict__ zqo, int* __restrict__ idxv,
    float* __restrict__ commit_part, float* __restrict__ valid_part) {

    __shared__ float s_best[4][64];
    __shared__ int   s_bk[4][64];

    const int lane = threadIdx.x & 63;
    const int wave = threadIdx.x >> 6;
    const int q    = blockIdx.x * 64 + lane;

    // load + normalize z row (kept fully in registers)
    float zr[C_];
    const float4* zp4 = (const float4*)(z + (size_t)q * C_);
    #pragma unroll
    for (int c4 = 0; c4 < 16; ++c4) {
        float4 v = zp4[c4];
        zr[c4 * 4 + 0] = v.x; zr[c4 * 4 + 1] = v.y;
        zr[c4 * 4 + 2] = v.z; zr[c4 * 4 + 3] = v.w;
    }
    float ss = 0.f;
    #pragma unroll
    for (int c = 0; c < C_; ++c) ss = fmaf(zr[c], zr[c], ss);
    float nrm = fmaxf(sqrtf(ss), 1e-12f);
    #pragma unroll
    for (int c = 0; c < C_; ++c) zr[c] = zr[c] / nrm;

    // scan this wave's 256-code partition, 4 codes at a time (4 indep FMA chains)
    float best = INFINITY;
    int   bk   = 0;
    const int kbeg = wave * 256;
    for (int k0 = kbeg; k0 < kbeg + 256; k0 += 4) {
        const size_t rb = (size_t)(k0 + 1) * C_;
        const float* r0 = cb + rb;
        const float* r1 = cb + rb + C_;
        const float* r2 = cb + rb + 2 * C_;
        const float* r3 = cb + (size_t)((k0 + 4 <= KE_) ? (k0 + 4) : KE_) * C_; // clamp row 1024->1023
        float d0 = 0.f, d1 = 0.f, d2 = 0.f, d3 = 0.f;
        #pragma unroll
        for (int c = 0; c < C_; ++c) {
            const float zc = zr[c];
            d0 = fmaf(zc, r0[c], d0);
            d1 = fmaf(zc, r1[c], d1);
            d2 = fmaf(zc, r2[c], d2);
            d3 = fmaf(zc, r3[c], d3);
        }
        const float v0 = fmaf(-2.f, d0, ee[k0 + 0]);
        const float v1 = fmaf(-2.f, d1, ee[k0 + 1]);
        const float v2 = fmaf(-2.f, d2, ee[k0 + 2]);
        const float v3 = fmaf(-2.f, d3, ee[k0 + 3]);   // ee[1023]=inf kills pad
        if (v0 < best) { best = v0; bk = k0 + 0; }
        if (v1 < best) { best = v1; bk = k0 + 1; }
        if (v2 < best) { best = v2; bk = k0 + 2; }
        if (v3 < best) { best = v3; bk = k0 + 3; }
    }

    s_best[wave][lane] = best;
    s_bk[wave][lane]   = bk;
    __syncthreads();

    if (threadIdx.x < 64) {   // wave 0 epilogue (its zr is valid for q)
        float bb = s_best[0][lane];
        int   bi = s_bk[0][lane];
        #pragma unroll
        for (int j = 1; j < 4; ++j) {
            float ob = s_best[j][lane];
            int   ok = s_bk[j][lane];
            if (ob < bb) { bb = ob; bi = ok; }   // ascending parts: first-min kept
        }
        const float m = mask[q];
        const float4* er = (const float4*)(cb + (size_t)(bi + 1) * C_);
        float4* zo = (float4*)(zqo + (size_t)q * C_);
        float commit = 0.f;
        #pragma unroll
        for (int c4 = 0; c4 < 16; ++c4) {
            float4 e4 = er[c4];
            float z0 = zr[c4 * 4 + 0], z1 = zr[c4 * 4 + 1];
            float z2 = zr[c4 * 4 + 2], z3 = zr[c4 * 4 + 3];
            float q0 = e4.x * m, q1 = e4.y * m, q2 = e4.z * m, q3 = e4.w * m;
            float4 o;
            o.x = (z0 + q0) - z0;   // straight-through forward value
            o.y = (z1 + q1) - z1;
            o.z = (z2 + q2) - z2;
            o.w = (z3 + q3) - z3;
            zo[c4] = o;
            float e0 = z0 - q0, e1 = z1 - q1, e2 = z2 - q2, e3 = z3 - q3;
            commit = fmaf(e0, e0, commit);
            commit = fmaf(e1, e1, commit);
            commit = fmaf(e2, e2, commit);
            commit = fmaf(e3, e3, commit);
        }
        commit *= m;
        idxv[q] = bi;
        float vc = m;
        #pragma unroll
        for (int off = 32; off > 0; off >>= 1) {
            commit += __shfl_down(commit, off);
            vc     += __shfl_down(vc, off);
        }
        if (lane == 0) {
            commit_part[blockIdx.x] = commit;
            valid_part[blockIdx.x]  = vc;
        }
    }
}

// ---- smoothness: sum (zqo[t]-zqo[t+1])^2 * mask[t+1], per-block partial ----
__global__ __launch_bounds__(256) void k_smooth(const float* __restrict__ zqo,
                                                const float* __restrict__ mask,
                                                float* __restrict__ smooth_part) {
    const int gid = blockIdx.x * 256 + threadIdx.x;
    const int TC1 = (T_ - 1) * C_;
    float val = 0.f;
    int b = gid / TC1;
    int rem = gid - b * TC1;
    int t = rem >> 6;
    int c = rem & 63;
    if (b < B_) {
        float m = mask[b * T_ + t + 1];
        if (m > 0.f) {
            size_t base = ((size_t)(b * T_ + t)) * C_ + c;
            float d = zqo[base] - zqo[base + C_];
            val = d * d;
        }
    }
    __shared__ float red[256];
    red[threadIdx.x] = val;
    __syncthreads();
    for (int off = 128; off > 0; off >>= 1) {
        if (threadIdx.x < off) red[threadIdx.x] += red[threadIdx.x + off];
        __syncthreads();
    }
    if (threadIdx.x == 0) smooth_part[blockIdx.x] = red[0];
}

// ---- per-batch start compaction: is_start prefix-sum -> selpos, n ----
__global__ __launch_bounds__(256) void k_scan(const int* __restrict__ idxv,
                                              const float* __restrict__ mask,
                                              int* __restrict__ selpos,
                                              int* __restrict__ nst) {
    __shared__ int sdata[256];
    __shared__ int s_carry;
    const int b = blockIdx.x;
    const int tid = threadIdx.x;
    if (tid == 0) s_carry = 0;
    __syncthreads();
    for (int chunk = 0; chunk < T_ / 256; ++chunk) {
        int t = chunk * 256 + tid;
        int is;
        if (t == 0) {
            is = 1;
        } else {
            int cur = idxv[b * T_ + t];
            int prv = idxv[b * T_ + t - 1];
            is = (cur != prv && mask[b * T_ + t] > 0.f) ? 1 : 0;
        }
        sdata[tid] = is;
        __syncthreads();
        for (int off = 1; off < 256; off <<= 1) {
            int add = (tid >= off) ? sdata[tid - off] : 0;
            __syncthreads();
            sdata[tid] += add;
            __syncthreads();
        }
        int incl = sdata[tid];
        int base = s_carry;
        if (is) selpos[b * T_ + base + incl - 1] = t;
        __syncthreads();
        if (tid == 255) s_carry = base + incl;
        __syncthreads();
    }
    if (tid == 0) nst[b] = s_carry;
}

// ---- n_z_q gather (writes ALL elements; zeros past n) ----
__global__ __launch_bounds__(256) void k_gather(const float* __restrict__ zqo,
                                                const int* __restrict__ selpos,
                                                const int* __restrict__ nst,
                                                float* __restrict__ nzq) {
    const int gid = blockIdx.x * 256 + threadIdx.x;
    const int b = gid >> 18;            // T*C = 2^18
    const int rem = gid & ((1 << 18) - 1);
    const int j = rem >> 6;
    const int c = rem & 63;
    float v = 0.f;
    if (j < nst[b]) {
        int p = selpos[b * T_ + j];
        v = zqo[((size_t)(b * T_ + p)) * C_ + c];
    }
    nzq[gid] = v;
}

// ---- n_mask + selected_encodings (as float) ----
__global__ __launch_bounds__(256) void k_sel(const int* __restrict__ idxv,
                                             const int* __restrict__ selpos,
                                             const int* __restrict__ nst,
                                             float* __restrict__ nmask,
                                             float* __restrict__ sel) {
    const int gid = blockIdx.x * 256 + threadIdx.x;
    const int b = gid >> 12;            // T = 2^12
    const int j = gid & (T_ - 1);
    float nm = 0.f, s = 0.f;
    if (j < nst[b]) {
        int p = selpos[gid];            // b*T + j == gid
        nm = 1.f;
        s = (float)(idxv[b * T_ + p] + 1);
    }
    nmask[gid] = nm;
    sel[gid] = s;
}

// ---- final reduction of partials -> losses ----
__global__ __launch_bounds__(256) void k_final(const float* __restrict__ commit_part,
                                               const float* __restrict__ valid_part,
                                               const float* __restrict__ smooth_part,
                                               float* __restrict__ out) {
    __shared__ double rc[256];
    __shared__ double rv[256];
    __shared__ double rs[256];
    const int tid = threadIdx.x;
    double sc = 0.0, sv = 0.0, ssm = 0.0;
    for (int i = tid; i < NBLK_ASSIGN; i += 256) {
        sc += (double)commit_part[i];
        sv += (double)valid_part[i];
    }
    for (int i = tid; i < NBLK_SMOOTH; i += 256) ssm += (double)smooth_part[i];
    rc[tid] = sc; rv[tid] = sv; rs[tid] = ssm;
    __syncthreads();
    for (int off = 128; off > 0; off >>= 1) {
        if (tid < off) {
            rc[tid] += rc[tid + off];
            rv[tid] += rv[tid + off];
            rs[tid] += rs[tid + off];
        }
        __syncthreads();
    }
    if (tid == 0) {
        double valid = rv[0];
        out[0] = (float)(rs[0] / (valid - (double)B_));  // m1.sum() = valid - B
        out[1] = (float)(rc[0] / valid);
    }
}

extern "C" void kernel_launch(void* const* d_in, const int* in_sizes, int n_in,
                              void* d_out, int out_size, void* d_ws, size_t ws_size,
                              hipStream_t stream) {
    const float* z    = (const float*)d_in[0];
    const float* cb   = (const float*)d_in[1];
    const float* mask = (const float*)d_in[2];
    float* out = (float*)d_out;
    char* ws = (char*)d_ws;

    float* ee          = (float*)(ws + 64);
    int*   idxv        = (int*)(ws + 4160);
    int*   selpos      = (int*)(ws + 266304);
    int*   nst         = (int*)(ws + 528448);
    float* commit_part = (float*)(ws + 528512);
    float* valid_part  = (float*)(ws + 532608);
    float* smooth_part = (float*)(ws + 536704);

    float* zqo   = out + 2;
    float* nzq   = zqo + (size_t)BT_ * C_;
    float* nmask = nzq + (size_t)BT_ * C_;
    float* sel   = nmask + BT_;

    k_ee    <<<4,            256, 0, stream>>>(cb, ee);
    k_assign<<<NBLK_ASSIGN,  256, 0, stream>>>(z, cb, mask, ee, zqo, idxv,
                                               commit_part, valid_part);
    k_smooth<<<NBLK_SMOOTH,  256, 0, stream>>>(zqo, mask, smooth_part);
    k_scan  <<<B_,           256, 0, stream>>>(idxv, mask, selpos, nst);
    k_gather<<<16384,        256, 0, stream>>>(zqo, selpos, nst, nzq);
    k_sel   <<<256,          256, 0, stream>>>(idxv, selpos, nst, nmask, sel);
    k_final <<<1,            256, 0, stream>>>(commit_part, valid_part,
                                               smooth_part, out);
}

// Round 2
// 418.327 us; speedup vs baseline: 2.0024x; 2.0024x over previous
//
#include <hip/hip_runtime.h>
#include <math.h>

#define B_  16
#define T_  4096
#define C_  64
#define K_  1024
#define KE_ 1023
#define BT_ (B_ * T_)

#define NBLK_ASSIGN 256             // 256 queries per block, 1 query/thread
#define NBLK_SMOOTH 16380           // B*(T-1)*C / 256
#define TILE_K 128
#define NTILE  8                    // 1024 padded codes / 128

// ---------------- ws layout (bytes) ----------------
// [64,    4160)   float ee[1024]        (|e_k|^2, ee[1023] = +inf pad)
// [4160,  266304) int   idxv[BT]
// [266304,528448) int   selpos[BT]
// [528448,528512) int   nst[B]
// [528512,532608) float commit_part[<=1024]
// [532608,536704) float valid_part[<=1024]
// [536704,602240) float smooth_part[16384]

// ---- |e_k|^2 precompute (k indexes e = codebook[1:], 1023 rows) ----
__global__ __launch_bounds__(256) void k_ee(const float* __restrict__ cb,
                                            float* __restrict__ ee) {
    int k = blockIdx.x * 256 + threadIdx.x;
    if (k < KE_) {
        const float* r = cb + (size_t)(k + 1) * C_;
        float s = 0.f;
        #pragma unroll
        for (int c = 0; c < C_; ++c) s = fmaf(r[c], r[c], s);
        ee[k] = s;
    } else if (k == KE_) {
        ee[k] = INFINITY;           // pad so k=1023 never wins
    }
}

// ---- hot kernel: normalize + argmin via LDS-staged codebook tiles ----
// 256 threads/block, 1 query/thread. Codebook staged in 128-code LDS tiles;
// during compute every lane reads the SAME LDS address (broadcast, no
// conflicts), and the LDS pipe runs parallel to the VALU FMA stream.
// 4 codes at a time -> 4 independent FMA chains hide the 4-cyc dep latency.
__global__ __launch_bounds__(256) void k_assign(
    const float* __restrict__ z, const float* __restrict__ cb,
    const float* __restrict__ mask, const float* __restrict__ ee,
    float* __restrict__ zqo, int* __restrict__ idxv,
    float* __restrict__ commit_part, float* __restrict__ valid_part) {

    __shared__ float s_e[TILE_K * C_];   // 32 KB code tile
    __shared__ float s_ee[TILE_K];       // |e|^2 tile (reused for reduction)

    const int tid  = threadIdx.x;
    const int lane = tid & 63;
    const int wave = tid >> 6;
    const int q    = blockIdx.x * 256 + tid;

    // load + normalize z row (registers)
    float4 zr4[16];
    const float4* zp4 = (const float4*)(z + (size_t)q * C_);
    float ss = 0.f;
    #pragma unroll
    for (int i = 0; i < 16; ++i) {
        float4 v = zp4[i];
        zr4[i] = v;
        ss = fmaf(v.x, v.x, ss);
        ss = fmaf(v.y, v.y, ss);
        ss = fmaf(v.z, v.z, ss);
        ss = fmaf(v.w, v.w, ss);
    }
    const float nrm = fmaxf(sqrtf(ss), 1e-12f);
    #pragma unroll
    for (int i = 0; i < 16; ++i) {
        zr4[i].x /= nrm; zr4[i].y /= nrm; zr4[i].z /= nrm; zr4[i].w /= nrm;
    }

    float best = INFINITY;
    int   bk   = 0;

    for (int tile = 0; tile < NTILE; ++tile) {
        __syncthreads();   // previous tile fully consumed before overwrite
        // stage 128 code rows (cb rows tile*128+1 .. +128, clamped at 1023)
        #pragma unroll
        for (int j = 0; j < 8; ++j) {
            int f    = j * 256 + tid;          // float4 index within tile
            int row  = f >> 4;                 // code within tile
            int k    = tile * TILE_K + row;
            int crow = (k + 1 <= KE_) ? (k + 1) : KE_;   // clamp pad row
            ((float4*)s_e)[f] = ((const float4*)cb)[crow * 16 + (f & 15)];
        }
        if (tid < TILE_K) s_ee[tid] = ee[tile * TILE_K + tid];  // inf at pad
        __syncthreads();

        #pragma unroll 1
        for (int kk = 0; kk < TILE_K; kk += 4) {
            const float4* r0 = (const float4*)(s_e + (size_t)(kk + 0) * C_);
            const float4* r1 = (const float4*)(s_e + (size_t)(kk + 1) * C_);
            const float4* r2 = (const float4*)(s_e + (size_t)(kk + 2) * C_);
            const float4* r3 = (const float4*)(s_e + (size_t)(kk + 3) * C_);
            float d0 = 0.f, d1 = 0.f, d2 = 0.f, d3 = 0.f;
            #pragma unroll
            for (int c4 = 0; c4 < 16; ++c4) {
                const float4 zz = zr4[c4];
                const float4 a0 = r0[c4];
                const float4 a1 = r1[c4];
                const float4 a2 = r2[c4];
                const float4 a3 = r3[c4];
                d0 = fmaf(zz.x, a0.x, d0); d0 = fmaf(zz.y, a0.y, d0);
                d0 = fmaf(zz.z, a0.z, d0); d0 = fmaf(zz.w, a0.w, d0);
                d1 = fmaf(zz.x, a1.x, d1); d1 = fmaf(zz.y, a1.y, d1);
                d1 = fmaf(zz.z, a1.z, d1); d1 = fmaf(zz.w, a1.w, d1);
                d2 = fmaf(zz.x, a2.x, d2); d2 = fmaf(zz.y, a2.y, d2);
                d2 = fmaf(zz.z, a2.z, d2); d2 = fmaf(zz.w, a2.w, d2);
                d3 = fmaf(zz.x, a3.x, d3); d3 = fmaf(zz.y, a3.y, d3);
                d3 = fmaf(zz.z, a3.z, d3); d3 = fmaf(zz.w, a3.w, d3);
            }
            const int kb = tile * TILE_K + kk;
            const float v0 = fmaf(-2.f, d0, s_ee[kk + 0]);
            const float v1 = fmaf(-2.f, d1, s_ee[kk + 1]);
            const float v2 = fmaf(-2.f, d2, s_ee[kk + 2]);
            const float v3 = fmaf(-2.f, d3, s_ee[kk + 3]);   // inf at pad
            if (v0 < best) { best = v0; bk = kb + 0; }
            if (v1 < best) { best = v1; bk = kb + 1; }
            if (v2 < best) { best = v2; bk = kb + 2; }
            if (v3 < best) { best = v3; bk = kb + 3; }
        }
    }

    // ---- per-thread epilogue (identical arithmetic to the verified R1) ----
    const float m  = mask[q];
    const int   bi = bk;
    const float4* er = (const float4*)(cb + (size_t)(bi + 1) * C_);
    float4* zo = (float4*)(zqo + (size_t)q * C_);
    float commit = 0.f;
    #pragma unroll
    for (int c4 = 0; c4 < 16; ++c4) {
        float4 e4 = er[c4];
        float z0 = zr4[c4].x, z1 = zr4[c4].y, z2 = zr4[c4].z, z3 = zr4[c4].w;
        float q0 = e4.x * m, q1 = e4.y * m, q2 = e4.z * m, q3 = e4.w * m;
        float4 o;
        o.x = (z0 + q0) - z0;   // straight-through forward value
        o.y = (z1 + q1) - z1;
        o.z = (z2 + q2) - z2;
        o.w = (z3 + q3) - z3;
        zo[c4] = o;
        float e0 = z0 - q0, e1 = z1 - q1, e2 = z2 - q2, e3 = z3 - q3;
        commit = fmaf(e0, e0, commit);
        commit = fmaf(e1, e1, commit);
        commit = fmaf(e2, e2, commit);
        commit = fmaf(e3, e3, commit);
    }
    commit *= m;
    idxv[q] = bi;

    // wave reduce, then 4-wave combine via LDS (s_ee reused after barrier)
    float vc = m;
    #pragma unroll
    for (int off = 32; off > 0; off >>= 1) {
        commit += __shfl_down(commit, off);
        vc     += __shfl_down(vc, off);
    }
    __syncthreads();
    if (lane == 0) { s_ee[wave] = commit; s_ee[4 + wave] = vc; }
    __syncthreads();
    if (tid == 0) {
        commit_part[blockIdx.x] = s_ee[0] + s_ee[1] + s_ee[2] + s_ee[3];
        valid_part[blockIdx.x]  = s_ee[4] + s_ee[5] + s_ee[6] + s_ee[7];
    }
}

// ---- smoothness: sum (zqo[t]-zqo[t+1])^2 * mask[t+1], per-block partial ----
__global__ __launch_bounds__(256) void k_smooth(const float* __restrict__ zqo,
                                                const float* __restrict__ mask,
                                                float* __restrict__ smooth_part) {
    const int gid = blockIdx.x * 256 + threadIdx.x;
    const int TC1 = (T_ - 1) * C_;
    float val = 0.f;
    int b = gid / TC1;
    int rem = gid - b * TC1;
    int t = rem >> 6;
    int c = rem & 63;
    if (b < B_) {
        float m = mask[b * T_ + t + 1];
        if (m > 0.f) {
            size_t base = ((size_t)(b * T_ + t)) * C_ + c;
            float d = zqo[base] - zqo[base + C_];
            val = d * d;
        }
    }
    __shared__ float red[256];
    red[threadIdx.x] = val;
    __syncthreads();
    for (int off = 128; off > 0; off >>= 1) {
        if (threadIdx.x < off) red[threadIdx.x] += red[threadIdx.x + off];
        __syncthreads();
    }
    if (threadIdx.x == 0) smooth_part[blockIdx.x] = red[0];
}

// ---- per-batch start compaction: is_start prefix-sum -> selpos, n ----
__global__ __launch_bounds__(256) void k_scan(const int* __restrict__ idxv,
                                              const float* __restrict__ mask,
                                              int* __restrict__ selpos,
                                              int* __restrict__ nst) {
    __shared__ int sdata[256];
    __shared__ int s_carry;
    const int b = blockIdx.x;
    const int tid = threadIdx.x;
    if (tid == 0) s_carry = 0;
    __syncthreads();
    for (int chunk = 0; chunk < T_ / 256; ++chunk) {
        int t = chunk * 256 + tid;
        int is;
        if (t == 0) {
            is = 1;
        } else {
            int cur = idxv[b * T_ + t];
            int prv = idxv[b * T_ + t - 1];
            is = (cur != prv && mask[b * T_ + t] > 0.f) ? 1 : 0;
        }
        sdata[tid] = is;
        __syncthreads();
        for (int off = 1; off < 256; off <<= 1) {
            int add = (tid >= off) ? sdata[tid - off] : 0;
            __syncthreads();
            sdata[tid] += add;
            __syncthreads();
        }
        int incl = sdata[tid];
        int base = s_carry;
        if (is) selpos[b * T_ + base + incl - 1] = t;
        __syncthreads();
        if (tid == 255) s_carry = base + incl;
        __syncthreads();
    }
    if (tid == 0) nst[b] = s_carry;
}

// ---- n_z_q gather (writes ALL elements; zeros past n) ----
__global__ __launch_bounds__(256) void k_gather(const float* __restrict__ zqo,
                                                const int* __restrict__ selpos,
                                                const int* __restrict__ nst,
                                                float* __restrict__ nzq) {
    const int gid = blockIdx.x * 256 + threadIdx.x;
    const int b = gid >> 18;            // T*C = 2^18
    const int rem = gid & ((1 << 18) - 1);
    const int j = rem >> 6;
    const int c = rem & 63;
    float v = 0.f;
    if (j < nst[b]) {
        int p = selpos[b * T_ + j];
        v = zqo[((size_t)(b * T_ + p)) * C_ + c];
    }
    nzq[gid] = v;
}

// ---- n_mask + selected_encodings (as float) ----
__global__ __launch_bounds__(256) void k_sel(const int* __restrict__ idxv,
                                             const int* __restrict__ selpos,
                                             const int* __restrict__ nst,
                                             float* __restrict__ nmask,
                                             float* __restrict__ sel) {
    const int gid = blockIdx.x * 256 + threadIdx.x;
    const int b = gid >> 12;            // T = 2^12
    const int j = gid & (T_ - 1);
    float nm = 0.f, s = 0.f;
    if (j < nst[b]) {
        int p = selpos[gid];            // b*T + j == gid
        nm = 1.f;
        s = (float)(idxv[b * T_ + p] + 1);
    }
    nmask[gid] = nm;
    sel[gid] = s;
}

// ---- final reduction of partials -> losses ----
__global__ __launch_bounds__(256) void k_final(const float* __restrict__ commit_part,
                                               const float* __restrict__ valid_part,
                                               const float* __restrict__ smooth_part,
                                               float* __restrict__ out) {
    __shared__ double rc[256];
    __shared__ double rv[256];
    __shared__ double rs[256];
    const int tid = threadIdx.x;
    double sc = 0.0, sv = 0.0, ssm = 0.0;
    for (int i = tid; i < NBLK_ASSIGN; i += 256) {
        sc += (double)commit_part[i];
        sv += (double)valid_part[i];
    }
    for (int i = tid; i < NBLK_SMOOTH; i += 256) ssm += (double)smooth_part[i];
    rc[tid] = sc; rv[tid] = sv; rs[tid] = ssm;
    __syncthreads();
    for (int off = 128; off > 0; off >>= 1) {
        if (tid < off) {
            rc[tid] += rc[tid + off];
            rv[tid] += rv[tid + off];
            rs[tid] += rs[tid + off];
        }
        __syncthreads();
    }
    if (tid == 0) {
        double valid = rv[0];
        out[0] = (float)(rs[0] / (valid - (double)B_));  // m1.sum() = valid - B
        out[1] = (float)(rc[0] / valid);
    }
}

extern "C" void kernel_launch(void* const* d_in, const int* in_sizes, int n_in,
                              void* d_out, int out_size, void* d_ws, size_t ws_size,
                              hipStream_t stream) {
    const float* z    = (const float*)d_in[0];
    const float* cb   = (const float*)d_in[1];
    const float* mask = (const float*)d_in[2];
    float* out = (float*)d_out;
    char* ws = (char*)d_ws;

    float* ee          = (float*)(ws + 64);
    int*   idxv        = (int*)(ws + 4160);
    int*   selpos      = (int*)(ws + 266304);
    int*   nst         = (int*)(ws + 528448);
    float* commit_part = (float*)(ws + 528512);
    float* valid_part  = (float*)(ws + 532608);
    float* smooth_part = (float*)(ws + 536704);

    float* zqo   = out + 2;
    float* nzq   = zqo + (size_t)BT_ * C_;
    float* nmask = nzq + (size_t)BT_ * C_;
    float* sel   = nmask + BT_;

    k_ee    <<<4,            256, 0, stream>>>(cb, ee);
    k_assign<<<NBLK_ASSIGN,  256, 0, stream>>>(z, cb, mask, ee, zqo, idxv,
                                               commit_part, valid_part);
    k_smooth<<<NBLK_SMOOTH,  256, 0, stream>>>(zqo, mask, smooth_part);
    k_scan  <<<B_,           256, 0, stream>>>(idxv, mask, selpos, nst);
    k_gather<<<16384,        256, 0, stream>>>(zqo, selpos, nst, nzq);
    k_sel   <<<256,          256, 0, stream>>>(idxv, selpos, nst, nmask, sel);
    k_final <<<1,            256, 0, stream>>>(commit_part, valid_part,
                                               smooth_part, out);
}

// Round 3
// 273.923 us; speedup vs baseline: 3.0580x; 1.5272x over previous
//
#include <hip/hip_runtime.h>
#include <math.h>

#define B_  16
#define T_  4096
#define C_  64
#define K_  1024
#define KE_ 1023
#define BT_ (B_ * T_)

#define QBLK    128            // query blocks (512 queries each, 2/thread)
#define KSPLIT  4              // code splits of 256 codes
#define KS_     256            // codes per split (padded K=1024)
#define TILE    64             // codes per LDS tile (16 KB)
#define NBLK_EPI 256
#define NBLK_SMOOTH 16380      // B*(T-1)*C / 256

// ---------------- ws layout (bytes) ----------------
// [64,      4160)    float ee[1024]            (|e_k|^2, ee[1023]=+inf pad)
// [4224,    528512)  u64   packed[BT]          (order(dist)<<32 | idx)
// [528512,  790656)  int   idxv[BT]
// [790656,  1052800) int   selpos[BT]
// [1052800, 1052864) int   nst[B]
// [1052864, 1053888) float commit_part[256]
// [1053888, 1054912) float valid_part[256]
// [1054912, 1120448) float smooth_part[16384]

__device__ __forceinline__ unsigned long long packkey(float d, int k) {
    unsigned int u = __float_as_uint(d);
    u = (u & 0x80000000u) ? ~u : (u | 0x80000000u);   // monotone total order
    return ((unsigned long long)u << 32) | (unsigned int)k;
}

// ---- |e_k|^2 precompute (k indexes e = codebook[1:], 1023 rows) ----
__global__ __launch_bounds__(256) void k_ee(const float* __restrict__ cb,
                                            float* __restrict__ ee) {
    int k = blockIdx.x * 256 + threadIdx.x;
    if (k < KE_) {
        const float* r = cb + (size_t)(k + 1) * C_;
        float s = 0.f;
        #pragma unroll
        for (int c = 0; c < C_; ++c) s = fmaf(r[c], r[c], s);
        ee[k] = s;
    } else if (k == KE_) {
        ee[k] = INFINITY;           // pad so k=1023 never wins
    }
}

// ---- hot kernel: 2 queries/thread, 4-way K-split, LDS 64-code tiles ----
// grid = QBLK * KSPLIT = 512 blocks. Each staged code row feeds 8 FMAs
// (2 queries x 4 floats) per ds_read_b128 -> VALU-bound, not LDS-bound.
// Result per (query, split): packed (orderdist<<32|k) via atomicMin.
__global__ __launch_bounds__(256, 2) void k_assign(
    const float* __restrict__ z, const float* __restrict__ cb,
    const float* __restrict__ ee, unsigned long long* __restrict__ packed) {

    __shared__ float s_e[TILE * C_];    // 16 KB
    __shared__ float s_ee[TILE];

    const int tid = threadIdx.x;
    const int qb  = blockIdx.x & (QBLK - 1);
    const int ks  = blockIdx.x >> 7;
    const int ksbase = ks * KS_;
    const int q0 = qb * 512 + tid;
    const int q1 = q0 + 256;

    // load + normalize both z rows into registers
    float4 zq0[16], zq1[16];
    {
        const float4* p0 = (const float4*)(z + (size_t)q0 * C_);
        const float4* p1 = (const float4*)(z + (size_t)q1 * C_);
        float s0 = 0.f, s1 = 0.f;
        #pragma unroll
        for (int i = 0; i < 16; ++i) {
            float4 a = p0[i], b = p1[i];
            zq0[i] = a; zq1[i] = b;
            s0 = fmaf(a.x, a.x, s0); s0 = fmaf(a.y, a.y, s0);
            s0 = fmaf(a.z, a.z, s0); s0 = fmaf(a.w, a.w, s0);
            s1 = fmaf(b.x, b.x, s1); s1 = fmaf(b.y, b.y, s1);
            s1 = fmaf(b.z, b.z, s1); s1 = fmaf(b.w, b.w, s1);
        }
        const float n0 = fmaxf(sqrtf(s0), 1e-12f);
        const float n1 = fmaxf(sqrtf(s1), 1e-12f);
        #pragma unroll
        for (int i = 0; i < 16; ++i) {
            zq0[i].x /= n0; zq0[i].y /= n0; zq0[i].z /= n0; zq0[i].w /= n0;
            zq1[i].x /= n1; zq1[i].y /= n1; zq1[i].z /= n1; zq1[i].w /= n1;
        }
    }

    float b0 = INFINITY, b1 = INFINITY;
    int   i0 = 0,        i1 = 0;

    for (int tile = 0; tile < KS_ / TILE; ++tile) {
        const int tbase = ksbase + tile * TILE;
        __syncthreads();
        // stage 64 code rows: 1024 float4, 4 per thread
        #pragma unroll
        for (int j = 0; j < 4; ++j) {
            int f    = j * 256 + tid;
            int row  = f >> 4;
            int k    = tbase + row;
            int crow = (k + 1 <= KE_) ? (k + 1) : KE_;   // clamp pad row
            ((float4*)s_e)[f] = ((const float4*)cb)[crow * 16 + (f & 15)];
        }
        if (tid < TILE) s_ee[tid] = ee[tbase + tid];     // inf at pad
        __syncthreads();

        #pragma unroll 1
        for (int kk = 0; kk < TILE; kk += 4) {
            const float4* r0 = (const float4*)(s_e + (kk + 0) * C_);
            const float4* r1 = (const float4*)(s_e + (kk + 1) * C_);
            const float4* r2 = (const float4*)(s_e + (kk + 2) * C_);
            const float4* r3 = (const float4*)(s_e + (kk + 3) * C_);
            float d00 = 0.f, d01 = 0.f, d02 = 0.f, d03 = 0.f;
            float d10 = 0.f, d11 = 0.f, d12 = 0.f, d13 = 0.f;
            #pragma unroll
            for (int c4 = 0; c4 < 16; ++c4) {
                const float4 a0 = r0[c4];
                const float4 a1 = r1[c4];
                const float4 a2 = r2[c4];
                const float4 a3 = r3[c4];
                const float4 x  = zq0[c4];
                const float4 y  = zq1[c4];
                d00 = fmaf(x.x, a0.x, d00); d00 = fmaf(x.y, a0.y, d00);
                d00 = fmaf(x.z, a0.z, d00); d00 = fmaf(x.w, a0.w, d00);
                d01 = fmaf(x.x, a1.x, d01); d01 = fmaf(x.y, a1.y, d01);
                d01 = fmaf(x.z, a1.z, d01); d01 = fmaf(x.w, a1.w, d01);
                d02 = fmaf(x.x, a2.x, d02); d02 = fmaf(x.y, a2.y, d02);
                d02 = fmaf(x.z, a2.z, d02); d02 = fmaf(x.w, a2.w, d02);
                d03 = fmaf(x.x, a3.x, d03); d03 = fmaf(x.y, a3.y, d03);
                d03 = fmaf(x.z, a3.z, d03); d03 = fmaf(x.w, a3.w, d03);
                d10 = fmaf(y.x, a0.x, d10); d10 = fmaf(y.y, a0.y, d10);
                d10 = fmaf(y.z, a0.z, d10); d10 = fmaf(y.w, a0.w, d10);
                d11 = fmaf(y.x, a1.x, d11); d11 = fmaf(y.y, a1.y, d11);
                d11 = fmaf(y.z, a1.z, d11); d11 = fmaf(y.w, a1.w, d11);
                d12 = fmaf(y.x, a2.x, d12); d12 = fmaf(y.y, a2.y, d12);
                d12 = fmaf(y.z, a2.z, d12); d12 = fmaf(y.w, a2.w, d12);
                d13 = fmaf(y.x, a3.x, d13); d13 = fmaf(y.y, a3.y, d13);
                d13 = fmaf(y.z, a3.z, d13); d13 = fmaf(y.w, a3.w, d13);
            }
            const int kb = tbase + kk;
            const float e0 = s_ee[kk + 0], e1 = s_ee[kk + 1];
            const float e2 = s_ee[kk + 2], e3 = s_ee[kk + 3];
            float v;
            v = fmaf(-2.f, d00, e0); if (v < b0) { b0 = v; i0 = kb + 0; }
            v = fmaf(-2.f, d01, e1); if (v < b0) { b0 = v; i0 = kb + 1; }
            v = fmaf(-2.f, d02, e2); if (v < b0) { b0 = v; i0 = kb + 2; }
            v = fmaf(-2.f, d03, e3); if (v < b0) { b0 = v; i0 = kb + 3; }
            v = fmaf(-2.f, d10, e0); if (v < b1) { b1 = v; i1 = kb + 0; }
            v = fmaf(-2.f, d11, e1); if (v < b1) { b1 = v; i1 = kb + 1; }
            v = fmaf(-2.f, d12, e2); if (v < b1) { b1 = v; i1 = kb + 2; }
            v = fmaf(-2.f, d13, e3); if (v < b1) { b1 = v; i1 = kb + 3; }
        }
    }

    atomicMin(&packed[q0], packkey(b0, i0));
    atomicMin(&packed[q1], packkey(b1, i1));
}

// ---- epilogue: unpack idx, re-normalize z, write z_q + commit partials ----
__global__ __launch_bounds__(256) void k_epi(
    const float* __restrict__ z, const float* __restrict__ cb,
    const float* __restrict__ mask, const unsigned long long* __restrict__ packed,
    float* __restrict__ zqo, int* __restrict__ idxv,
    float* __restrict__ commit_part, float* __restrict__ valid_part) {

    __shared__ float s_red[8];
    const int tid  = threadIdx.x;
    const int lane = tid & 63;
    const int wave = tid >> 6;
    const int q    = blockIdx.x * 256 + tid;

    const int bi = (int)(unsigned int)(packed[q] & 0xFFFFFFFFull);
    const float m = mask[q];
    idxv[q] = bi;

    const float4* zp = (const float4*)(z + (size_t)q * C_);
    const float4* er = (const float4*)(cb + (size_t)(bi + 1) * C_);
    float4* zo = (float4*)(zqo + (size_t)q * C_);

    float4 zr[16];
    float ss = 0.f;
    #pragma unroll
    for (int i = 0; i < 16; ++i) {
        float4 v = zp[i];
        zr[i] = v;
        ss = fmaf(v.x, v.x, ss); ss = fmaf(v.y, v.y, ss);
        ss = fmaf(v.z, v.z, ss); ss = fmaf(v.w, v.w, ss);
    }
    const float nrm = fmaxf(sqrtf(ss), 1e-12f);
    float commit = 0.f;
    #pragma unroll
    for (int i = 0; i < 16; ++i) {
        float z0 = zr[i].x / nrm, z1 = zr[i].y / nrm;
        float z2 = zr[i].z / nrm, z3 = zr[i].w / nrm;
        float4 e4 = er[i];
        float q0 = e4.x * m, q1 = e4.y * m, q2 = e4.z * m, q3 = e4.w * m;
        float4 o;
        o.x = (z0 + q0) - z0;   // straight-through forward value
        o.y = (z1 + q1) - z1;
        o.z = (z2 + q2) - z2;
        o.w = (z3 + q3) - z3;
        zo[i] = o;
        float e0 = z0 - q0, e1 = z1 - q1, e2 = z2 - q2, e3 = z3 - q3;
        commit = fmaf(e0, e0, commit);
        commit = fmaf(e1, e1, commit);
        commit = fmaf(e2, e2, commit);
        commit = fmaf(e3, e3, commit);
    }
    commit *= m;

    float vc = m;
    #pragma unroll
    for (int off = 32; off > 0; off >>= 1) {
        commit += __shfl_down(commit, off);
        vc     += __shfl_down(vc, off);
    }
    if (lane == 0) { s_red[wave] = commit; s_red[4 + wave] = vc; }
    __syncthreads();
    if (tid == 0) {
        commit_part[blockIdx.x] = s_red[0] + s_red[1] + s_red[2] + s_red[3];
        valid_part[blockIdx.x]  = s_red[4] + s_red[5] + s_red[6] + s_red[7];
    }
}

// ---- smoothness: sum (zqo[t]-zqo[t+1])^2 * mask[t+1], per-block partial ----
__global__ __launch_bounds__(256) void k_smooth(const float* __restrict__ zqo,
                                                const float* __restrict__ mask,
                                                float* __restrict__ smooth_part) {
    const int gid = blockIdx.x * 256 + threadIdx.x;
    const int TC1 = (T_ - 1) * C_;
    float val = 0.f;
    int b = gid / TC1;
    int rem = gid - b * TC1;
    int t = rem >> 6;
    int c = rem & 63;
    if (b < B_) {
        float m = mask[b * T_ + t + 1];
        if (m > 0.f) {
            size_t base = ((size_t)(b * T_ + t)) * C_ + c;
            float d = zqo[base] - zqo[base + C_];
            val = d * d;
        }
    }
    __shared__ float red[256];
    red[threadIdx.x] = val;
    __syncthreads();
    for (int off = 128; off > 0; off >>= 1) {
        if (threadIdx.x < off) red[threadIdx.x] += red[threadIdx.x + off];
        __syncthreads();
    }
    if (threadIdx.x == 0) smooth_part[blockIdx.x] = red[0];
}

// ---- per-batch start compaction: 16 t/thread, single block scan ----
__global__ __launch_bounds__(256) void k_scan(const int* __restrict__ idxv,
                                              const float* __restrict__ mask,
                                              int* __restrict__ selpos,
                                              int* __restrict__ nst) {
    __shared__ int cnt[256];
    const int b = blockIdx.x;
    const int tid = threadIdx.x;
    const int base = b * T_;
    const int t0 = tid * 16;

    int flags = 0, c = 0;
    int prev = (tid == 0) ? -1 : idxv[base + t0 - 1];
    #pragma unroll
    for (int i = 0; i < 16; ++i) {
        const int t = t0 + i;
        const int cur = idxv[base + t];
        const int is = (t == 0) ? 1
                     : ((cur != prev && mask[base + t] > 0.f) ? 1 : 0);
        flags |= is << i;
        c += is;
        prev = cur;
    }
    cnt[tid] = c;
    __syncthreads();
    for (int off = 1; off < 256; off <<= 1) {
        int add = (tid >= off) ? cnt[tid - off] : 0;
        __syncthreads();
        cnt[tid] += add;
        __syncthreads();
    }
    int pos = cnt[tid] - c;   // exclusive prefix
    #pragma unroll
    for (int i = 0; i < 16; ++i) {
        if ((flags >> i) & 1) selpos[base + pos++] = t0 + i;
    }
    if (tid == 255) nst[b] = cnt[255];
}

// ---- n_z_q gather (writes ALL elements; zeros past n) ----
__global__ __launch_bounds__(256) void k_gather(const float* __restrict__ zqo,
                                                const int* __restrict__ selpos,
                                                const int* __restrict__ nst,
                                                float* __restrict__ nzq) {
    const int gid = blockIdx.x * 256 + threadIdx.x;
    const int b = gid >> 18;            // T*C = 2^18
    const int rem = gid & ((1 << 18) - 1);
    const int j = rem >> 6;
    const int c = rem & 63;
    float v = 0.f;
    if (j < nst[b]) {
        int p = selpos[b * T_ + j];
        v = zqo[((size_t)(b * T_ + p)) * C_ + c];
    }
    nzq[gid] = v;
}

// ---- n_mask + selected_encodings (as float) ----
__global__ __launch_bounds__(256) void k_sel(const int* __restrict__ idxv,
                                             const int* __restrict__ selpos,
                                             const int* __restrict__ nst,
                                             float* __restrict__ nmask,
                                             float* __restrict__ sel) {
    const int gid = blockIdx.x * 256 + threadIdx.x;
    const int b = gid >> 12;            // T = 2^12
    const int j = gid & (T_ - 1);
    float nm = 0.f, s = 0.f;
    if (j < nst[b]) {
        int p = selpos[gid];            // b*T + j == gid
        nm = 1.f;
        s = (float)(idxv[b * T_ + p] + 1);
    }
    nmask[gid] = nm;
    sel[gid] = s;
}

// ---- final reduction of partials -> losses ----
__global__ __launch_bounds__(256) void k_final(const float* __restrict__ commit_part,
                                               const float* __restrict__ valid_part,
                                               const float* __restrict__ smooth_part,
                                               float* __restrict__ out) {
    __shared__ double rc[256];
    __shared__ double rv[256];
    __shared__ double rs[256];
    const int tid = threadIdx.x;
    double sc = 0.0, sv = 0.0, ssm = 0.0;
    for (int i = tid; i < NBLK_EPI; i += 256) {
        sc += (double)commit_part[i];
        sv += (double)valid_part[i];
    }
    for (int i = tid; i < NBLK_SMOOTH; i += 256) ssm += (double)smooth_part[i];
    rc[tid] = sc; rv[tid] = sv; rs[tid] = ssm;
    __syncthreads();
    for (int off = 128; off > 0; off >>= 1) {
        if (tid < off) {
            rc[tid] += rc[tid + off];
            rv[tid] += rv[tid + off];
            rs[tid] += rs[tid + off];
        }
        __syncthreads();
    }
    if (tid == 0) {
        double valid = rv[0];
        out[0] = (float)(rs[0] / (valid - (double)B_));  // m1.sum() = valid - B
        out[1] = (float)(rc[0] / valid);
    }
}

extern "C" void kernel_launch(void* const* d_in, const int* in_sizes, int n_in,
                              void* d_out, int out_size, void* d_ws, size_t ws_size,
                              hipStream_t stream) {
    const float* z    = (const float*)d_in[0];
    const float* cb   = (const float*)d_in[1];
    const float* mask = (const float*)d_in[2];
    float* out = (float*)d_out;
    char* ws = (char*)d_ws;

    float*              ee          = (float*)(ws + 64);
    unsigned long long* packed      = (unsigned long long*)(ws + 4224);
    int*                idxv        = (int*)(ws + 528512);
    int*                selpos      = (int*)(ws + 790656);
    int*                nst         = (int*)(ws + 1052800);
    float*              commit_part = (float*)(ws + 1052864);
    float*              valid_part  = (float*)(ws + 1053888);
    float*              smooth_part = (float*)(ws + 1054912);

    float* zqo   = out + 2;
    float* nzq   = zqo + (size_t)BT_ * C_;
    float* nmask = nzq + (size_t)BT_ * C_;
    float* sel   = nmask + BT_;

    hipMemsetAsync(packed, 0xFF, (size_t)BT_ * 8, stream);  // max-key init
    k_ee    <<<4,             256, 0, stream>>>(cb, ee);
    k_assign<<<QBLK * KSPLIT, 256, 0, stream>>>(z, cb, ee, packed);
    k_epi   <<<NBLK_EPI,      256, 0, stream>>>(z, cb, mask, packed, zqo, idxv,
                                                commit_part, valid_part);
    k_smooth<<<NBLK_SMOOTH,   256, 0, stream>>>(zqo, mask, smooth_part);
    k_scan  <<<B_,            256, 0, stream>>>(idxv, mask, selpos, nst);
    k_gather<<<16384,         256, 0, stream>>>(zqo, selpos, nst, nzq);
    k_sel   <<<256,           256, 0, stream>>>(idxv, selpos, nst, nmask, sel);
    k_final <<<1,             256, 0, stream>>>(commit_part, valid_part,
                                                smooth_part, out);
}